// Round 1
// 1517.774 us; speedup vs baseline: 1.6422x; 1.6422x over previous
//
#include <hip/hip_runtime.h>
#include <cstdint>
#include <cstddef>

// Problem constants: B=4, S=2048, IN=4096, OUT=11008, GROUP=128
#define M_TOT 8192
#define N_TOT 11008
#define K_TOT 4096
#define WROW_PACK 2048   // packed int32 per W row = K/2
#define NG 32            // groups per row = K/128

#define NBN (N_TOT / 128)          // 86 N-tiles
#define NBM (M_TOT / 128)          // 64 M-tiles
#define NWG (NBN * NBM)            // 5504 blocks (5504 % 8 == 0 -> simple XCD swizzle bijective)

typedef __attribute__((ext_vector_type(8))) short short8;   // bf16x8 MFMA operand (4 VGPRs)
typedef __attribute__((ext_vector_type(4))) float f32x4;    // MFMA accumulator
typedef unsigned short ushort_t;

// (bf16(hi) << 16) | bf16(lo), truncation rounding, single v_perm_b32.
// Numerics identical to the previously-passing kernel.
__device__ __forceinline__ unsigned int pack2_bf16(float lo, float hi) {
    return __builtin_amdgcn_perm(__float_as_uint(hi), __float_as_uint(lo), 0x07060302u);
}

// One packed byte (int32 value 0..255) -> two dequantized bf16 weights.
// High nibble is the earlier K index (matches torch.stack([high, low], -1)).
__device__ __forceinline__ unsigned int dequant_pair(int q, float s, float z) {
    float wh = (float)(q >> 4) * s + z;
    float wl = (float)(q & 15) * s + z;
    return pack2_bf16(wh, wl);            // wh at lower address (earlier k)
}

// Direct global->LDS DMA, 16B per lane. LDS dest must be wave-uniform base + lane*16.
__device__ __forceinline__ void gload_lds16(const void* g, void* l) {
    __builtin_amdgcn_global_load_lds(
        (const __attribute__((address_space(1))) unsigned int*)g,
        (__attribute__((address_space(3))) unsigned int*)l,
        16, 0, 0);
}

// ---------------------------------------------------------------------------
// Pass 1a: x fp32 -> bf16 (memory-bound, ~32 us). 8 floats / thread.
// ---------------------------------------------------------------------------
__global__ __launch_bounds__(256)
void convert_x_kernel(const float4* __restrict__ xin, uint4* __restrict__ xout) {
    const size_t t = (size_t)blockIdx.x * 256 + threadIdx.x;
    const float4 v0 = xin[2 * t];
    const float4 v1 = xin[2 * t + 1];
    xout[t] = make_uint4(pack2_bf16(v0.x, v0.y), pack2_bf16(v0.z, v0.w),
                         pack2_bf16(v1.x, v1.y), pack2_bf16(v1.z, v1.w));
}

// ---------------------------------------------------------------------------
// Pass 1b: W packed-int4 -> bf16 [N][K] row-major, dequantized ONCE
// (vs. 64x redundantly inside the old fused loop). ~29 us.
// One int4 (4 packed bytes -> 8 weights) per thread; all 8 weights share a
// group (64 int32 per group, int4-aligned).
// ---------------------------------------------------------------------------
__global__ __launch_bounds__(256)
void dequant_w_kernel(const int4* __restrict__ wq4,
                      const float* __restrict__ wsc,
                      const float* __restrict__ wzp,
                      uint4* __restrict__ wout) {
    const size_t t = (size_t)blockIdx.x * 256 + threadIdx.x;   // < 11008*512
    const int row = (int)(t >> 9);        // / (WROW_PACK/4 = 512)
    const int c4  = (int)(t & 511);
    const int g   = c4 >> 4;              // (c4*8)/128
    const float s = wsc[(size_t)row * NG + g];
    const float z = wzp[(size_t)row * NG + g];
    const int4 q = wq4[t];
    wout[t] = make_uint4(dequant_pair(q.x, s, z), dequant_pair(q.y, s, z),
                         dequant_pair(q.z, s, z), dequant_pair(q.w, s, z));
}

// ---------------------------------------------------------------------------
// Pass 2: bf16 GEMM, m97 structure: 128x128 tile, BK=32, single-buffered LDS,
// width-16 global_load_lds staging, 4 waves (2x2), 4x4 grid of 16x16x32 MFMA
// per wave. Linear (unpadded) LDS — required by global_load_lds; T2 swizzle is
// measured-null at 128^2+2phase (regime gate), so no conflict fix needed here.
// ---------------------------------------------------------------------------
__global__ __launch_bounds__(256, 2)
void gemm_bf16_kernel(const ushort_t* __restrict__ A,   // [M][K] bf16
                      const ushort_t* __restrict__ B,   // [N][K] bf16
                      float* __restrict__ out)
{
    __shared__ __align__(16) ushort_t As[128 * 32];   // 8 KiB
    __shared__ __align__(16) ushort_t Bs[128 * 32];   // 8 KiB

    const int tid  = threadIdx.x;
    const int lane = tid & 63;
    const int wv   = tid >> 6;
    const int wm   = wv >> 1;          // wave row (M)
    const int wn   = wv & 1;           // wave col (N)
    const int l15  = lane & 15;
    const int quad = lane >> 4;

    // Bijective XCD-aware swizzle (T1): NWG % 8 == 0, +10% at 8k-scale (m192).
    const int bid = blockIdx.x;
    const int swz = (bid & 7) * (NWG >> 3) + (bid >> 3);
    const int bm  = swz / NBN;
    const int bn  = swz % NBN;
    const size_t m0 = (size_t)bm * 128;
    const size_t n0 = (size_t)bn * 128;

    // Staging: tile = 128 rows x 32 bf16 = 8 KiB = 2 rounds x 256 threads x 16B.
    // Element e covers LDS bytes [e*16, e*16+16) = row (e>>2), k-chunk (e&3)*8.
    // Lane-consecutive e -> LDS base + lane*16: satisfies the gload_lds layout rule.
    const int e0 = tid;
    const int e1 = 256 + tid;
    const ushort_t* ga0 = A + (m0 + (e0 >> 2)) * K_TOT + (e0 & 3) * 8;
    const ushort_t* ga1 = A + (m0 + (e1 >> 2)) * K_TOT + (e1 & 3) * 8;
    const ushort_t* gb0 = B + (n0 + (e0 >> 2)) * K_TOT + (e0 & 3) * 8;
    const ushort_t* gb1 = B + (n0 + (e1 >> 2)) * K_TOT + (e1 & 3) * 8;
    ushort_t* la0 = &As[e0 * 8];
    ushort_t* la1 = &As[e1 * 8];
    ushort_t* lb0 = &Bs[e0 * 8];
    ushort_t* lb1 = &Bs[e1 * 8];

    f32x4 acc[4][4];
#pragma unroll
    for (int i = 0; i < 4; ++i)
#pragma unroll
        for (int j = 0; j < 4; ++j)
            acc[i][j] = (f32x4)(0.0f);

    for (int kt = 0; kt < K_TOT / 32; ++kt) {
        gload_lds16(ga0, la0);
        gload_lds16(ga1, la1);
        gload_lds16(gb0, lb0);
        gload_lds16(gb1, lb1);
        ga0 += 32; ga1 += 32; gb0 += 32; gb1 += 32;   // advance BK=32 bf16

        __syncthreads();   // compiler emits vmcnt(0) drain before s_barrier

        short8 af[4], bfr[4];
#pragma unroll
        for (int mi = 0; mi < 4; ++mi)
            af[mi] = *reinterpret_cast<const short8*>(
                &As[(wm * 64 + mi * 16 + l15) * 32 + quad * 8]);
#pragma unroll
        for (int ni = 0; ni < 4; ++ni)
            bfr[ni] = *reinterpret_cast<const short8*>(
                &Bs[(wn * 64 + ni * 16 + l15) * 32 + quad * 8]);
#pragma unroll
        for (int mi = 0; mi < 4; ++mi)
#pragma unroll
            for (int ni = 0; ni < 4; ++ni)
                acc[mi][ni] = __builtin_amdgcn_mfma_f32_16x16x32_bf16(
                    af[mi], bfr[ni], acc[mi][ni], 0, 0, 0);

        __syncthreads();
    }

    // Epilogue: C/D layout col=lane&15, row=quad*4+reg (verified m89/m91).
#pragma unroll
    for (int mi = 0; mi < 4; ++mi) {
        const size_t row_base = m0 + wm * 64 + mi * 16 + quad * 4;
#pragma unroll
        for (int r = 0; r < 4; ++r) {
            float* dst = out + (row_base + r) * N_TOT + n0 + wn * 64 + l15;
#pragma unroll
            for (int ni = 0; ni < 4; ++ni)
                dst[ni * 16] = acc[mi][ni][r];
        }
    }
}

// ---------------------------------------------------------------------------
// Fallback: previous fused kernel (verbatim) — used only if workspace is too
// small for the bf16 staging buffers. Guarantees no regression.
// ---------------------------------------------------------------------------
#define BK 32
#define LDA 40

__global__ __launch_bounds__(256, 2)
void qlinear_kernel(const float* __restrict__ x,
                    const int*   __restrict__ wq,
                    const float* __restrict__ wsc,
                    const float* __restrict__ wzp,
                    float*       __restrict__ out)
{
    __shared__ unsigned short As[128 * LDA];
    __shared__ unsigned short Bs[128 * LDA];

    const int tid  = threadIdx.x;
    const int lane = tid & 63;
    const int wv   = tid >> 6;
    const int wm   = wv >> 1;
    const int wn   = wv & 1;
    const int l15  = lane & 15;
    const int quad = lane >> 4;

    const int n0 = blockIdx.x * 128;
    const int m0 = blockIdx.y * 128;

    const int ar  = tid >> 3;
    const int ac4 = tid & 7;
    const int br  = tid >> 2;
    const int bc  = tid & 3;

    const float4* a_ptrs[4];
#pragma unroll
    for (int i = 0; i < 4; ++i)
        a_ptrs[i] = reinterpret_cast<const float4*>(
                        x + (size_t)(m0 + ar + 32 * i) * K_TOT) + ac4;
    const int4* b_ptrs[2];
#pragma unroll
    for (int i = 0; i < 2; ++i)
        b_ptrs[i] = reinterpret_cast<const int4*>(
                        wq + (size_t)(n0 + br + 64 * i) * WROW_PACK) + bc;

    f32x4 acc[4][4];
#pragma unroll
    for (int i = 0; i < 4; ++i)
#pragma unroll
        for (int j = 0; j < 4; ++j)
            acc[i][j] = (f32x4)(0.0f);

    float s0 = 0.f, z0 = 0.f, s1 = 0.f, z1 = 0.f;

    for (int kt = 0; kt < K_TOT / BK; ++kt) {
        if ((kt & 3) == 0) {
            const int g = kt >> 2;
            s0 = wsc[(size_t)(n0 + br) * NG + g];
            z0 = wzp[(size_t)(n0 + br) * NG + g];
            s1 = wsc[(size_t)(n0 + br + 64) * NG + g];
            z1 = wzp[(size_t)(n0 + br + 64) * NG + g];
        }

#pragma unroll
        for (int i = 0; i < 4; ++i) {
            float4 v = a_ptrs[i][0];
            a_ptrs[i] += 8;
            unsigned int p0 = pack2_bf16(v.x, v.y);
            unsigned int p1 = pack2_bf16(v.z, v.w);
            *reinterpret_cast<uint2*>(&As[(ar + 32 * i) * LDA + ac4 * 4]) =
                make_uint2(p0, p1);
        }

#pragma unroll
        for (int i = 0; i < 2; ++i) {
            int4 q = b_ptrs[i][0];
            b_ptrs[i] += 4;
            const float s = i ? s1 : s0;
            const float z = i ? z1 : z0;
            unsigned int w01 = dequant_pair(q.x, s, z);
            unsigned int w23 = dequant_pair(q.y, s, z);
            unsigned int w45 = dequant_pair(q.z, s, z);
            unsigned int w67 = dequant_pair(q.w, s, z);
            *reinterpret_cast<uint4*>(&Bs[(br + 64 * i) * LDA + bc * 8]) =
                make_uint4(w01, w23, w45, w67);
        }

        __syncthreads();

        short8 af[4], bfr[4];
#pragma unroll
        for (int mi = 0; mi < 4; ++mi)
            af[mi] = *reinterpret_cast<const short8*>(
                &As[(wm * 64 + mi * 16 + l15) * LDA + quad * 8]);
#pragma unroll
        for (int ni = 0; ni < 4; ++ni)
            bfr[ni] = *reinterpret_cast<const short8*>(
                &Bs[(wn * 64 + ni * 16 + l15) * LDA + quad * 8]);
#pragma unroll
        for (int mi = 0; mi < 4; ++mi)
#pragma unroll
            for (int ni = 0; ni < 4; ++ni)
                acc[mi][ni] = __builtin_amdgcn_mfma_f32_16x16x32_bf16(
                    af[mi], bfr[ni], acc[mi][ni], 0, 0, 0);

        __syncthreads();
    }

#pragma unroll
    for (int mi = 0; mi < 4; ++mi) {
        const int row_base = m0 + wm * 64 + mi * 16 + quad * 4;
#pragma unroll
        for (int r = 0; r < 4; ++r) {
            float* dst = out + (size_t)(row_base + r) * N_TOT
                             + n0 + wn * 64 + l15;
#pragma unroll
            for (int ni = 0; ni < 4; ++ni)
                dst[ni * 16] = acc[mi][ni][r];
        }
    }
}

extern "C" void kernel_launch(void* const* d_in, const int* in_sizes, int n_in,
                              void* d_out, int out_size, void* d_ws, size_t ws_size,
                              hipStream_t stream) {
    const float* x   = (const float*)d_in[0];
    const int*   wq  = (const int*)d_in[1];
    const float* wsc = (const float*)d_in[2];
    const float* wzp = (const float*)d_in[3];
    float* out = (float*)d_out;

    const size_t XB = (size_t)M_TOT * K_TOT * 2;   // 67,108,864 B  (x bf16)
    const size_t WB = (size_t)N_TOT * K_TOT * 2;   // 90,177,536 B  (W bf16)

    if (ws_size >= XB + WB) {
        ushort_t* xb = (ushort_t*)d_ws;
        ushort_t* wb = (ushort_t*)((char*)d_ws + XB);
        // 1a: x fp32->bf16. 8192*4096 / (256 threads * 8 floats) = 16384 blocks.
        convert_x_kernel<<<dim3(M_TOT * K_TOT / (256 * 8)), dim3(256), 0, stream>>>(
            (const float4*)x, (uint4*)xb);
        // 1b: W dequant. 11008*2048 int32 / (256 threads * 4 int32) = 22016 blocks.
        dequant_w_kernel<<<dim3(N_TOT * WROW_PACK / (256 * 4)), dim3(256), 0, stream>>>(
            (const int4*)wq, wsc, wzp, (uint4*)wb);
        // 2: bf16 GEMM, 5504 blocks.
        gemm_bf16_kernel<<<dim3(NWG), dim3(256), 0, stream>>>(xb, wb, out);
    } else {
        dim3 grid(N_TOT / 128, M_TOT / 128);
        qlinear_kernel<<<grid, dim3(256), 0, stream>>>(x, wq, wsc, wzp, out);
    }
}

// Round 2
// 1210.950 us; speedup vs baseline: 2.0583x; 1.2534x over previous
//
#include <hip/hip_runtime.h>
#include <cstdint>
#include <cstddef>

// Problem constants: B=4, S=2048, IN=4096, OUT=11008, GROUP=128
#define M_TOT 8192
#define N_TOT 11008
#define K_TOT 4096
#define WROW_PACK 2048   // packed int32 per W row = K/2
#define NG 32            // groups per row = K/128

// ---- GEMM geometry: 256x256 tile, BK=32, 8 waves (2M x 4N), 4-slot LDS ring
#define BM 256
#define BN 256
#define BKT 32
#define NSLOT 4
#define NT (K_TOT / BKT)           // 128 K-tiles
#define NBM2 (M_TOT / BM)          // 32
#define NBN2 (N_TOT / BN)          // 43
#define NWG2 (NBM2 * NBN2)         // 1376 (% 8 == 0 -> simple XCD swizzle bijective)
#define SLOT_USH 16384             // ushorts per ring slot (A 8192 + B 8192)
#define LDS_BYTES (NSLOT * SLOT_USH * 2)   // 131072 B

typedef __attribute__((ext_vector_type(8))) short short8;   // bf16x8 MFMA operand
typedef __attribute__((ext_vector_type(4))) float f32x4;    // MFMA accumulator
typedef unsigned short ushort_t;

// (bf16(hi) << 16) | bf16(lo), truncation rounding, single v_perm_b32.
__device__ __forceinline__ unsigned int pack2_bf16(float lo, float hi) {
    return __builtin_amdgcn_perm(__float_as_uint(hi), __float_as_uint(lo), 0x07060302u);
}

__device__ __forceinline__ unsigned int dequant_pair(int q, float s, float z) {
    float wh = (float)(q >> 4) * s + z;   // high nibble = earlier k
    float wl = (float)(q & 15) * s + z;
    return pack2_bf16(wh, wl);
}

// Direct global->LDS DMA, 16B per lane. LDS dest must be wave-uniform base + lane*16.
__device__ __forceinline__ void gload_lds16(const void* g, void* l) {
    __builtin_amdgcn_global_load_lds(
        (const __attribute__((address_space(1))) unsigned int*)g,
        (__attribute__((address_space(3))) unsigned int*)l,
        16, 0, 0);
}

// ---------------------------------------------------------------------------
// Pass 1a: x fp32 -> bf16.
// ---------------------------------------------------------------------------
__global__ __launch_bounds__(256)
void convert_x_kernel(const float4* __restrict__ xin, uint4* __restrict__ xout) {
    const size_t t = (size_t)blockIdx.x * 256 + threadIdx.x;
    const float4 v0 = xin[2 * t];
    const float4 v1 = xin[2 * t + 1];
    xout[t] = make_uint4(pack2_bf16(v0.x, v0.y), pack2_bf16(v0.z, v0.w),
                         pack2_bf16(v1.x, v1.y), pack2_bf16(v1.z, v1.w));
}

// ---------------------------------------------------------------------------
// Pass 1b: W packed-int4 -> bf16 [N][K] row-major, dequantized ONCE.
// ---------------------------------------------------------------------------
__global__ __launch_bounds__(256)
void dequant_w_kernel(const int4* __restrict__ wq4,
                      const float* __restrict__ wsc,
                      const float* __restrict__ wzp,
                      uint4* __restrict__ wout) {
    const size_t t = (size_t)blockIdx.x * 256 + threadIdx.x;
    const int row = (int)(t >> 9);
    const int c4  = (int)(t & 511);
    const int g   = c4 >> 4;
    const float s = wsc[(size_t)row * NG + g];
    const float z = wzp[(size_t)row * NG + g];
    const int4 q = wq4[t];
    wout[t] = make_uint4(dequant_pair(q.x, s, z), dequant_pair(q.y, s, z),
                         dequant_pair(q.z, s, z), dequant_pair(q.w, s, z));
}

// ---------------------------------------------------------------------------
// Pass 2: bf16 GEMM. 256x256 tile, BK=32, 512 threads (8 waves, 2Mx4N),
// 4-slot LDS ring (prefetch distance 3), counted vmcnt(8) + raw s_barrier
// (never drain-to-0 in the main loop), XOR chunk swizzle on both the staging
// global source and the ds_read address (linear gload_lds dest — rule 21),
// setprio around the MFMA cluster, bijective XCD block swizzle.
//
// Hazard ledger:
//  RAW: tile t's 4 loads issued at iter t-3 top; at end of iter t-1 the wait
//       vmcnt(8) allows only tiles t+1,t+2 outstanding -> t landed; barrier
//       publishes to all waves before iter t's ds_reads.
//  WAR: iter t issues into slot (t+3)&3 == (t-1)&3. Tile t-1's ds_reads were
//       data-returned (compiler lgkmcnt before its MFMAs) before every wave
//       reached the barrier ending iter t-1, which precedes this issue.
// ---------------------------------------------------------------------------
__global__ __launch_bounds__(512, 2)
void gemm_bf16_256(const ushort_t* __restrict__ A,   // [M][K] bf16
                   const ushort_t* __restrict__ B,   // [N][K] bf16
                   float* __restrict__ out)
{
    extern __shared__ ushort_t lds[];   // [NSLOT][A:8192 | B:8192] ushorts

    const int tid  = threadIdx.x;
    const int lane = tid & 63;
    const int wv   = tid >> 6;         // 0..7
    const int wm   = wv >> 2;          // 0..1  (M half)
    const int wn   = wv & 3;           // 0..3  (N quarter)
    const int l15  = lane & 15;
    const int quad = lane >> 4;

    // T1: bijective XCD swizzle (NWG2 % 8 == 0). Consecutive swz share bm ->
    // A-panel (2 MB) stays resident in the XCD's 4 MB L2.
    const int bid = blockIdx.x;
    const int swz = (bid & 7) * (NWG2 >> 3) + (bid >> 3);
    const int bm  = swz / NBN2;
    const int bn  = swz % NBN2;
    const size_t m0 = (size_t)bm * BM;
    const size_t n0 = (size_t)bn * BN;

    // Staging: element e = r*512 + tid covers LDS bytes [e*16, e*16+16) =
    // tile row (e>>2), PHYSICAL 16B chunk (e&3). Source fetches LOGICAL chunk
    // (e&3) ^ (row&3)  -> LDS holds the XOR-swizzled layout while the DMA
    // dest stays linear (wave-uniform base + lane*16).
    const int srow = tid >> 2;                    // rows 0..127 (e1: +128)
    const int lc   = (tid & 3) ^ (srow & 3);      // same for e1 (128 % 4 == 0)
    const ushort_t* ga0 = A + (m0 + srow) * (size_t)K_TOT + lc * 8;
    const ushort_t* gb0 = B + (n0 + srow) * (size_t)K_TOT + lc * 8;
    const ushort_t* ga1 = ga0 + (size_t)128 * K_TOT;
    const ushort_t* gb1 = gb0 + (size_t)128 * K_TOT;
    const int dst0 = tid * 8;          // ushort idx within region
    const int dst1 = dst0 + 4096;      // element 512+tid

    // Fragment read offsets (ushort idx within region). Logical k-chunk =
    // quad; physical = quad ^ (row&3); row&3 == l15&3 for all frag rows.
    const int pco = (quad ^ (l15 & 3)) * 8;
    int aoff[8], boff[4];
#pragma unroll
    for (int mi = 0; mi < 8; ++mi)
        aoff[mi] = (wm * 128 + mi * 16 + l15) * BKT + pco;
#pragma unroll
    for (int ni = 0; ni < 4; ++ni)
        boff[ni] = (wn * 64 + ni * 16 + l15) * BKT + pco;

    f32x4 acc[8][4];
#pragma unroll
    for (int i = 0; i < 8; ++i)
#pragma unroll
        for (int j = 0; j < 4; ++j)
            acc[i][j] = (f32x4)(0.0f);

    // ---- prologue: issue tiles 0,1,2; wait until tile 0 landed (vmcnt(8))
#pragma unroll
    for (int t = 0; t < 3; ++t) {
        ushort_t* sa = lds + t * SLOT_USH;
        ushort_t* sb = sa + 8192;
        const int ko = t * BKT;
        gload_lds16(ga0 + ko, sa + dst0);
        gload_lds16(ga1 + ko, sa + dst1);
        gload_lds16(gb0 + ko, sb + dst0);
        gload_lds16(gb1 + ko, sb + dst1);
    }
    asm volatile("s_waitcnt vmcnt(8)" ::: "memory");
    __builtin_amdgcn_s_barrier();

    // ---- main loop ----
#pragma unroll 1
    for (int t = 0; t < NT; ++t) {
        if (t + 3 < NT) {                        // issue tile t+3
            const int tp = t + 3;
            ushort_t* sa = lds + (tp & 3) * SLOT_USH;
            ushort_t* sb = sa + 8192;
            const int ko = tp * BKT;
            gload_lds16(ga0 + ko, sa + dst0);
            gload_lds16(ga1 + ko, sa + dst1);
            gload_lds16(gb0 + ko, sb + dst0);
            gload_lds16(gb1 + ko, sb + dst1);
        }

        const ushort_t* sa = lds + (t & 3) * SLOT_USH;
        const ushort_t* sb = sa + 8192;

        short8 af[8], bf[4];
#pragma unroll
        for (int mi = 0; mi < 8; ++mi)
            af[mi] = *reinterpret_cast<const short8*>(sa + aoff[mi]);
#pragma unroll
        for (int ni = 0; ni < 4; ++ni)
            bf[ni] = *reinterpret_cast<const short8*>(sb + boff[ni]);

        __builtin_amdgcn_s_setprio(1);
#pragma unroll
        for (int mi = 0; mi < 8; ++mi)
#pragma unroll
            for (int ni = 0; ni < 4; ++ni)
                acc[mi][ni] = __builtin_amdgcn_mfma_f32_16x16x32_bf16(
                    af[mi], bf[ni], acc[mi][ni], 0, 0, 0);
        __builtin_amdgcn_s_setprio(0);

        // counted wait: guarantee tile t+1 landed before the next barrier.
        if (t + 3 < NT) {
            asm volatile("s_waitcnt vmcnt(8)" ::: "memory");   // steady state
        } else if (t + 2 < NT) {
            asm volatile("s_waitcnt vmcnt(4)" ::: "memory");   // epilogue drain
        } else if (t + 1 < NT) {
            asm volatile("s_waitcnt vmcnt(0)" ::: "memory");
        }
        if (t + 1 < NT) __builtin_amdgcn_s_barrier();
    }

    // ---- epilogue: C/D layout col=lane&15, row=quad*4+reg (m89/m91) ----
#pragma unroll
    for (int mi = 0; mi < 8; ++mi) {
        const size_t row_base = m0 + wm * 128 + mi * 16 + quad * 4;
#pragma unroll
        for (int r = 0; r < 4; ++r) {
            float* dst = out + (row_base + r) * N_TOT + n0 + wn * 64 + l15;
#pragma unroll
            for (int ni = 0; ni < 4; ++ni)
                dst[ni * 16] = acc[mi][ni][r];
        }
    }
}

// ---------------------------------------------------------------------------
// Fallback: original fused kernel — used only if workspace is too small.
// ---------------------------------------------------------------------------
#define BK 32
#define LDA 40

__global__ __launch_bounds__(256, 2)
void qlinear_kernel(const float* __restrict__ x,
                    const int*   __restrict__ wq,
                    const float* __restrict__ wsc,
                    const float* __restrict__ wzp,
                    float*       __restrict__ out)
{
    __shared__ unsigned short As[128 * LDA];
    __shared__ unsigned short Bs[128 * LDA];

    const int tid  = threadIdx.x;
    const int lane = tid & 63;
    const int wv   = tid >> 6;
    const int wm   = wv >> 1;
    const int wn   = wv & 1;
    const int l15  = lane & 15;
    const int quad = lane >> 4;

    const int n0 = blockIdx.x * 128;
    const int m0 = blockIdx.y * 128;

    const int ar  = tid >> 3;
    const int ac4 = tid & 7;
    const int br  = tid >> 2;
    const int bc  = tid & 3;

    const float4* a_ptrs[4];
#pragma unroll
    for (int i = 0; i < 4; ++i)
        a_ptrs[i] = reinterpret_cast<const float4*>(
                        x + (size_t)(m0 + ar + 32 * i) * K_TOT) + ac4;
    const int4* b_ptrs[2];
#pragma unroll
    for (int i = 0; i < 2; ++i)
        b_ptrs[i] = reinterpret_cast<const int4*>(
                        wq + (size_t)(n0 + br + 64 * i) * WROW_PACK) + bc;

    f32x4 acc[4][4];
#pragma unroll
    for (int i = 0; i < 4; ++i)
#pragma unroll
        for (int j = 0; j < 4; ++j)
            acc[i][j] = (f32x4)(0.0f);

    float s0 = 0.f, z0 = 0.f, s1 = 0.f, z1 = 0.f;

    for (int kt = 0; kt < K_TOT / BK; ++kt) {
        if ((kt & 3) == 0) {
            const int g = kt >> 2;
            s0 = wsc[(size_t)(n0 + br) * NG + g];
            z0 = wzp[(size_t)(n0 + br) * NG + g];
            s1 = wsc[(size_t)(n0 + br + 64) * NG + g];
            z1 = wzp[(size_t)(n0 + br + 64) * NG + g];
        }

#pragma unroll
        for (int i = 0; i < 4; ++i) {
            float4 v = a_ptrs[i][0];
            a_ptrs[i] += 8;
            unsigned int p0 = pack2_bf16(v.x, v.y);
            unsigned int p1 = pack2_bf16(v.z, v.w);
            *reinterpret_cast<uint2*>(&As[(ar + 32 * i) * LDA + ac4 * 4]) =
                make_uint2(p0, p1);
        }

#pragma unroll
        for (int i = 0; i < 2; ++i) {
            int4 q = b_ptrs[i][0];
            b_ptrs[i] += 4;
            const float s = i ? s1 : s0;
            const float z = i ? z1 : z0;
            unsigned int w01 = dequant_pair(q.x, s, z);
            unsigned int w23 = dequant_pair(q.y, s, z);
            unsigned int w45 = dequant_pair(q.z, s, z);
            unsigned int w67 = dequant_pair(q.w, s, z);
            *reinterpret_cast<uint4*>(&Bs[(br + 64 * i) * LDA + bc * 8]) =
                make_uint4(w01, w23, w45, w67);
        }

        __syncthreads();

        short8 af[4], bfr[4];
#pragma unroll
        for (int mi = 0; mi < 4; ++mi)
            af[mi] = *reinterpret_cast<const short8*>(
                &As[(wm * 64 + mi * 16 + l15) * LDA + quad * 8]);
#pragma unroll
        for (int ni = 0; ni < 4; ++ni)
            bfr[ni] = *reinterpret_cast<const short8*>(
                &Bs[(wn * 64 + ni * 16 + l15) * LDA + quad * 8]);
#pragma unroll
        for (int mi = 0; mi < 4; ++mi)
#pragma unroll
            for (int ni = 0; ni < 4; ++ni)
                acc[mi][ni] = __builtin_amdgcn_mfma_f32_16x16x32_bf16(
                    af[mi], bfr[ni], acc[mi][ni], 0, 0, 0);

        __syncthreads();
    }

#pragma unroll
    for (int mi = 0; mi < 4; ++mi) {
        const int row_base = m0 + wm * 64 + mi * 16 + quad * 4;
#pragma unroll
        for (int r = 0; r < 4; ++r) {
            float* dst = out + (size_t)(row_base + r) * N_TOT
                             + n0 + wn * 64 + l15;
#pragma unroll
            for (int ni = 0; ni < 4; ++ni)
                dst[ni * 16] = acc[mi][ni][r];
        }
    }
}

extern "C" void kernel_launch(void* const* d_in, const int* in_sizes, int n_in,
                              void* d_out, int out_size, void* d_ws, size_t ws_size,
                              hipStream_t stream) {
    const float* x   = (const float*)d_in[0];
    const int*   wq  = (const int*)d_in[1];
    const float* wsc = (const float*)d_in[2];
    const float* wzp = (const float*)d_in[3];
    float* out = (float*)d_out;

    const size_t XB = (size_t)M_TOT * K_TOT * 2;   // x bf16
    const size_t WB = (size_t)N_TOT * K_TOT * 2;   // W bf16

    if (ws_size >= XB + WB) {
        static bool attr_set = false;
        if (!attr_set) {
            hipFuncSetAttribute(reinterpret_cast<const void*>(gemm_bf16_256),
                                hipFuncAttributeMaxDynamicSharedMemorySize,
                                LDS_BYTES);
            attr_set = true;
        }
        ushort_t* xb = (ushort_t*)d_ws;
        ushort_t* wb = (ushort_t*)((char*)d_ws + XB);
        convert_x_kernel<<<dim3(M_TOT * K_TOT / (256 * 8)), dim3(256), 0, stream>>>(
            (const float4*)x, (uint4*)xb);
        dequant_w_kernel<<<dim3(N_TOT * WROW_PACK / (256 * 4)), dim3(256), 0, stream>>>(
            (const int4*)wq, wsc, wzp, (uint4*)wb);
        gemm_bf16_256<<<dim3(NWG2), dim3(512), LDS_BYTES, stream>>>(xb, wb, out);
    } else {
        dim3 grid(N_TOT / 128, M_TOT / 128);
        qlinear_kernel<<<grid, dim3(256), 0, stream>>>(x, wq, wsc, wzp, out);
    }
}

// Round 3
// 1183.274 us; speedup vs baseline: 2.1064x; 1.0234x over previous
//
#include <hip/hip_runtime.h>
#include <cstdint>
#include <cstddef>

// Problem constants: B=4, S=2048, IN=4096, OUT=11008, GROUP=128
#define M_TOT 8192
#define N_TOT 11008
#define K_TOT 4096
#define WROW_PACK 2048   // packed int32 per W row = K/2
#define NG 32            // groups per row = K/128

// ---- GEMM geometry: 256x256 tile, BK=32, 8 waves (2M x 4N), 4-slot LDS ring
#define BM 256
#define BN 256
#define BKT 32
#define NSLOT 4
#define NT (K_TOT / BKT)           // 128 K-tiles
#define NBM2 (M_TOT / BM)          // 32
#define NBN2 (N_TOT / BN)          // 43
#define NWG2 (NBM2 * NBN2)         // 1376 (% 8 == 0 -> simple XCD swizzle bijective)
#define SLOT_USH 16384             // ushorts per ring slot (A 8192 + B 8192)
#define LDS_BYTES (NSLOT * SLOT_USH * 2)   // 131072 B

typedef __attribute__((ext_vector_type(8))) short short8;   // bf16x8 MFMA operand
typedef __attribute__((ext_vector_type(4))) float f32x4;    // MFMA accumulator
typedef unsigned short ushort_t;

// (bf16(hi) << 16) | bf16(lo), truncation rounding, single v_perm_b32.
__device__ __forceinline__ unsigned int pack2_bf16(float lo, float hi) {
    return __builtin_amdgcn_perm(__float_as_uint(hi), __float_as_uint(lo), 0x07060302u);
}

__device__ __forceinline__ unsigned int dequant_pair(int q, float s, float z) {
    float wh = (float)(q >> 4) * s + z;   // high nibble = earlier k
    float wl = (float)(q & 15) * s + z;
    return pack2_bf16(wh, wl);
}

// Direct global->LDS DMA, 16B per lane. LDS dest must be wave-uniform base + lane*16.
__device__ __forceinline__ void gload_lds16(const void* g, void* l) {
    __builtin_amdgcn_global_load_lds(
        (const __attribute__((address_space(1))) unsigned int*)g,
        (__attribute__((address_space(3))) unsigned int*)l,
        16, 0, 0);
}

// ---------------------------------------------------------------------------
// Pass 1a: x fp32 -> bf16.
// ---------------------------------------------------------------------------
__global__ __launch_bounds__(256)
void convert_x_kernel(const float4* __restrict__ xin, uint4* __restrict__ xout) {
    const size_t t = (size_t)blockIdx.x * 256 + threadIdx.x;
    const float4 v0 = xin[2 * t];
    const float4 v1 = xin[2 * t + 1];
    xout[t] = make_uint4(pack2_bf16(v0.x, v0.y), pack2_bf16(v0.z, v0.w),
                         pack2_bf16(v1.x, v1.y), pack2_bf16(v1.z, v1.w));
}

// ---------------------------------------------------------------------------
// Pass 1b: W packed-int4 -> bf16 [N][K] row-major, dequantized ONCE.
// ---------------------------------------------------------------------------
__global__ __launch_bounds__(256)
void dequant_w_kernel(const int4* __restrict__ wq4,
                      const float* __restrict__ wsc,
                      const float* __restrict__ wzp,
                      uint4* __restrict__ wout) {
    const size_t t = (size_t)blockIdx.x * 256 + threadIdx.x;
    const int row = (int)(t >> 9);
    const int c4  = (int)(t & 511);
    const int g   = c4 >> 4;
    const float s = wsc[(size_t)row * NG + g];
    const float z = wzp[(size_t)row * NG + g];
    const int4 q = wq4[t];
    wout[t] = make_uint4(dequant_pair(q.x, s, z), dequant_pair(q.y, s, z),
                         dequant_pair(q.z, s, z), dequant_pair(q.w, s, z));
}

// ---------------------------------------------------------------------------
// Pass 2: bf16 GEMM. 256x256 tile, BK=32, 512 threads (8 waves, 2Mx4N),
// 4-slot LDS ring (prefetch distance 3).
//
// Schedule (m201 8-phase template granularity: 16-MFMA phases, 2 raw barriers
// per phase, counted vmcnt once per K-step, setprio around MFMA clusters):
//   ph1: { ds_read af[0..3],bf[0..3] ; issue A(t+3) ; bar ; 16 MFMA ; bar }
//   ph2: { ds_read af[4..7]          ; issue B(t+3) ; vmcnt(8) ; bar ;
//          16 MFMA ; bar }
// Never drain vmcnt to 0 in the main loop.
//
// Bank swizzle (both-sides XOR, rule 21): physical chunk = logical ^ (row>>1)&3.
// Row = 64 B -> lane start bank = 16*(row&1) + 4*chunk. With this XOR each
// quarter-wave's 8 even-row lanes take every chunk value exactly 2x (banks
// 0-15, 2 dwords/bank) and odd rows cover banks 16-31 likewise: the 2-per-bank
// theoretical minimum (free per m136). The previous chunk^=(row&3) correlated
// with row&1 -> 4-way conflicts (measured 6.8e7).
//
// Hazard ledger:
//  RAW: tile t's loads issued during t-3; vmcnt(8) at t-1 leaves only tiles
//       t+1,t+2 outstanding -> t landed; barrier publishes before t's reads.
//  WAR: slot (t+3)&3 == (t-1)&3; overwrite issues after the barrier following
//       tile t-1's last ds_reads (data already returned to VGPRs pre-MFMA).
//  All barriers wave-uniform (conditions depend only on t).
// ---------------------------------------------------------------------------
__global__ __launch_bounds__(512, 2)
void gemm_bf16_256(const ushort_t* __restrict__ A,   // [M][K] bf16
                   const ushort_t* __restrict__ B,   // [N][K] bf16
                   float* __restrict__ out)
{
    extern __shared__ ushort_t lds[];   // [NSLOT][A:8192 | B:8192] ushorts

    const int tid  = threadIdx.x;
    const int lane = tid & 63;
    const int wv   = tid >> 6;         // 0..7
    const int wm   = wv >> 2;          // 0..1  (M half)
    const int wn   = wv & 3;           // 0..3  (N quarter)
    const int l15  = lane & 15;
    const int quad = lane >> 4;

    // T1: bijective XCD swizzle (NWG2 % 8 == 0).
    const int bid = blockIdx.x;
    const int swz = (bid & 7) * (NWG2 >> 3) + (bid >> 3);
    const int bm  = swz / NBN2;
    const int bn  = swz % NBN2;
    const size_t m0 = (size_t)bm * BM;
    const size_t n0 = (size_t)bn * BN;

    // Staging: element e = r*512 + tid covers LDS row (e>>2), PHYSICAL chunk
    // (e&3). Source fetches LOGICAL chunk (e&3) ^ ((row>>1)&3); DMA dest stays
    // linear. row>>1 for e1 (row=128+srow) equals srow>>1 mod 4 (128/2 % 4 == 0).
    const int srow = tid >> 2;                       // rows 0..127
    const int lc   = (tid & 3) ^ ((tid >> 3) & 3);   // (chunk) ^ ((srow>>1)&3)
    const ushort_t* ga0 = A + (m0 + srow) * (size_t)K_TOT + lc * 8;
    const ushort_t* gb0 = B + (n0 + srow) * (size_t)K_TOT + lc * 8;
    const ushort_t* ga1 = ga0 + (size_t)128 * K_TOT;
    const ushort_t* gb1 = gb0 + (size_t)128 * K_TOT;
    const int dst0 = tid * 8;          // ushort idx within region
    const int dst1 = dst0 + 4096;      // element 512+tid

    // Fragment read offsets. Logical k-chunk = quad; physical = quad ^
    // ((row>>1)&3); fragment base rows are multiples of 16 so (row>>1)&3 ==
    // (l15>>1)&3 for every fragment.
    const int pco = (quad ^ ((l15 >> 1) & 3)) * 8;
    int aoff[8], boff[4];
#pragma unroll
    for (int mi = 0; mi < 8; ++mi)
        aoff[mi] = (wm * 128 + mi * 16 + l15) * BKT + pco;
#pragma unroll
    for (int ni = 0; ni < 4; ++ni)
        boff[ni] = (wn * 64 + ni * 16 + l15) * BKT + pco;

    f32x4 acc[8][4];
#pragma unroll
    for (int i = 0; i < 8; ++i)
#pragma unroll
        for (int j = 0; j < 4; ++j)
            acc[i][j] = (f32x4)(0.0f);

    // ---- prologue: issue tiles 0,1,2; wait until tile 0 landed (vmcnt(8))
#pragma unroll
    for (int t = 0; t < 3; ++t) {
        ushort_t* sa = lds + t * SLOT_USH;
        ushort_t* sb = sa + 8192;
        const int ko = t * BKT;
        gload_lds16(ga0 + ko, sa + dst0);
        gload_lds16(ga1 + ko, sa + dst1);
        gload_lds16(gb0 + ko, sb + dst0);
        gload_lds16(gb1 + ko, sb + dst1);
    }
    asm volatile("s_waitcnt vmcnt(8)" ::: "memory");
    __builtin_amdgcn_s_barrier();

    // ---- main loop ----
#pragma unroll 1
    for (int t = 0; t < NT; ++t) {
        const bool pf = (t + 3 < NT);
        const int tp = t + 3;
        ushort_t* pa = lds + (tp & 3) * SLOT_USH;   // prefetch slot
        ushort_t* pb = pa + 8192;
        const int ko = tp * BKT;
        const ushort_t* sa = lds + (t & 3) * SLOT_USH;   // compute slot
        const ushort_t* sb = sa + 8192;

        // ======== phase 1: quadrant mi=0..3 ========
        short8 af0[4], bf[4];
#pragma unroll
        for (int mi = 0; mi < 4; ++mi)
            af0[mi] = *reinterpret_cast<const short8*>(sa + aoff[mi]);
#pragma unroll
        for (int ni = 0; ni < 4; ++ni)
            bf[ni] = *reinterpret_cast<const short8*>(sb + boff[ni]);
        if (pf) {
            gload_lds16(ga0 + ko, pa + dst0);
            gload_lds16(ga1 + ko, pa + dst1);
        }
        __builtin_amdgcn_s_barrier();
        __builtin_amdgcn_s_setprio(1);
#pragma unroll
        for (int mi = 0; mi < 4; ++mi)
#pragma unroll
            for (int ni = 0; ni < 4; ++ni)
                acc[mi][ni] = __builtin_amdgcn_mfma_f32_16x16x32_bf16(
                    af0[mi], bf[ni], acc[mi][ni], 0, 0, 0);
        __builtin_amdgcn_s_setprio(0);
        __builtin_amdgcn_s_barrier();

        // ======== phase 2: quadrant mi=4..7 ========
        short8 af1[4];
#pragma unroll
        for (int mi = 0; mi < 4; ++mi)
            af1[mi] = *reinterpret_cast<const short8*>(sa + aoff[4 + mi]);
        if (pf) {
            gload_lds16(gb0 + ko, pb + dst0);
            gload_lds16(gb1 + ko, pb + dst1);
        }
        // counted wait, once per K-step: guarantee tile t+1 landed.
        if (t + 3 < NT) {
            asm volatile("s_waitcnt vmcnt(8)" ::: "memory");   // steady state
        } else if (t + 2 < NT) {
            asm volatile("s_waitcnt vmcnt(4)" ::: "memory");   // drain
        } else if (t + 1 < NT) {
            asm volatile("s_waitcnt vmcnt(0)" ::: "memory");
        }
        __builtin_amdgcn_s_barrier();
        __builtin_amdgcn_s_setprio(1);
#pragma unroll
        for (int mi = 0; mi < 4; ++mi)
#pragma unroll
            for (int ni = 0; ni < 4; ++ni)
                acc[4 + mi][ni] = __builtin_amdgcn_mfma_f32_16x16x32_bf16(
                    af1[mi], bf[ni], acc[4 + mi][ni], 0, 0, 0);
        __builtin_amdgcn_s_setprio(0);
        if (t + 1 < NT) __builtin_amdgcn_s_barrier();
    }

    // ---- epilogue: C/D layout col=lane&15, row=quad*4+reg (m89/m91) ----
#pragma unroll
    for (int mi = 0; mi < 8; ++mi) {
        const size_t row_base = m0 + wm * 128 + mi * 16 + quad * 4;
#pragma unroll
        for (int r = 0; r < 4; ++r) {
            float* dst = out + (row_base + r) * N_TOT + n0 + wn * 64 + l15;
#pragma unroll
            for (int ni = 0; ni < 4; ++ni)
                dst[ni * 16] = acc[mi][ni][r];
        }
    }
}

// ---------------------------------------------------------------------------
// Fallback: original fused kernel — used only if workspace is too small.
// ---------------------------------------------------------------------------
#define BK 32
#define LDA 40

__global__ __launch_bounds__(256, 2)
void qlinear_kernel(const float* __restrict__ x,
                    const int*   __restrict__ wq,
                    const float* __restrict__ wsc,
                    const float* __restrict__ wzp,
                    float*       __restrict__ out)
{
    __shared__ unsigned short As[128 * LDA];
    __shared__ unsigned short Bs[128 * LDA];

    const int tid  = threadIdx.x;
    const int lane = tid & 63;
    const int wv   = tid >> 6;
    const int wm   = wv >> 1;
    const int wn   = wv & 1;
    const int l15  = lane & 15;
    const int quad = lane >> 4;

    const int n0 = blockIdx.x * 128;
    const int m0 = blockIdx.y * 128;

    const int ar  = tid >> 3;
    const int ac4 = tid & 7;
    const int br  = tid >> 2;
    const int bc  = tid & 3;

    const float4* a_ptrs[4];
#pragma unroll
    for (int i = 0; i < 4; ++i)
        a_ptrs[i] = reinterpret_cast<const float4*>(
                        x + (size_t)(m0 + ar + 32 * i) * K_TOT) + ac4;
    const int4* b_ptrs[2];
#pragma unroll
    for (int i = 0; i < 2; ++i)
        b_ptrs[i] = reinterpret_cast<const int4*>(
                        wq + (size_t)(n0 + br + 64 * i) * WROW_PACK) + bc;

    f32x4 acc[4][4];
#pragma unroll
    for (int i = 0; i < 4; ++i)
#pragma unroll
        for (int j = 0; j < 4; ++j)
            acc[i][j] = (f32x4)(0.0f);

    float s0 = 0.f, z0 = 0.f, s1 = 0.f, z1 = 0.f;

    for (int kt = 0; kt < K_TOT / BK; ++kt) {
        if ((kt & 3) == 0) {
            const int g = kt >> 2;
            s0 = wsc[(size_t)(n0 + br) * NG + g];
            z0 = wzp[(size_t)(n0 + br) * NG + g];
            s1 = wsc[(size_t)(n0 + br + 64) * NG + g];
            z1 = wzp[(size_t)(n0 + br + 64) * NG + g];
        }

#pragma unroll
        for (int i = 0; i < 4; ++i) {
            float4 v = a_ptrs[i][0];
            a_ptrs[i] += 8;
            unsigned int p0 = pack2_bf16(v.x, v.y);
            unsigned int p1 = pack2_bf16(v.z, v.w);
            *reinterpret_cast<uint2*>(&As[(ar + 32 * i) * LDA + ac4 * 4]) =
                make_uint2(p0, p1);
        }

#pragma unroll
        for (int i = 0; i < 2; ++i) {
            int4 q = b_ptrs[i][0];
            b_ptrs[i] += 4;
            const float s = i ? s1 : s0;
            const float z = i ? z1 : z0;
            unsigned int w01 = dequant_pair(q.x, s, z);
            unsigned int w23 = dequant_pair(q.y, s, z);
            unsigned int w45 = dequant_pair(q.z, s, z);
            unsigned int w67 = dequant_pair(q.w, s, z);
            *reinterpret_cast<uint4*>(&Bs[(br + 64 * i) * LDA + bc * 8]) =
                make_uint4(w01, w23, w45, w67);
        }

        __syncthreads();

        short8 af[4], bfr[4];
#pragma unroll
        for (int mi = 0; mi < 4; ++mi)
            af[mi] = *reinterpret_cast<const short8*>(
                &As[(wm * 64 + mi * 16 + l15) * LDA + quad * 8]);
#pragma unroll
        for (int ni = 0; ni < 4; ++ni)
            bfr[ni] = *reinterpret_cast<const short8*>(
                &Bs[(wn * 64 + ni * 16 + l15) * LDA + quad * 8]);
#pragma unroll
        for (int mi = 0; mi < 4; ++mi)
#pragma unroll
            for (int ni = 0; ni < 4; ++ni)
                acc[mi][ni] = __builtin_amdgcn_mfma_f32_16x16x32_bf16(
                    af[mi], bfr[ni], acc[mi][ni], 0, 0, 0);

        __syncthreads();
    }

#pragma unroll
    for (int mi = 0; mi < 4; ++mi) {
        const int row_base = m0 + wm * 64 + mi * 16 + quad * 4;
#pragma unroll
        for (int r = 0; r < 4; ++r) {
            float* dst = out + (size_t)(row_base + r) * N_TOT
                             + n0 + wn * 64 + l15;
#pragma unroll
            for (int ni = 0; ni < 4; ++ni)
                dst[ni * 16] = acc[mi][ni][r];
        }
    }
}

extern "C" void kernel_launch(void* const* d_in, const int* in_sizes, int n_in,
                              void* d_out, int out_size, void* d_ws, size_t ws_size,
                              hipStream_t stream) {
    const float* x   = (const float*)d_in[0];
    const int*   wq  = (const int*)d_in[1];
    const float* wsc = (const float*)d_in[2];
    const float* wzp = (const float*)d_in[3];
    float* out = (float*)d_out;

    const size_t XB = (size_t)M_TOT * K_TOT * 2;   // x bf16
    const size_t WB = (size_t)N_TOT * K_TOT * 2;   // W bf16

    if (ws_size >= XB + WB) {
        static bool attr_set = false;
        if (!attr_set) {
            hipFuncSetAttribute(reinterpret_cast<const void*>(gemm_bf16_256),
                                hipFuncAttributeMaxDynamicSharedMemorySize,
                                LDS_BYTES);
            attr_set = true;
        }
        ushort_t* xb = (ushort_t*)d_ws;
        ushort_t* wb = (ushort_t*)((char*)d_ws + XB);
        convert_x_kernel<<<dim3(M_TOT * K_TOT / (256 * 8)), dim3(256), 0, stream>>>(
            (const float4*)x, (uint4*)xb);
        dequant_w_kernel<<<dim3(N_TOT * WROW_PACK / (256 * 4)), dim3(256), 0, stream>>>(
            (const int4*)wq, wsc, wzp, (uint4*)wb);
        gemm_bf16_256<<<dim3(NWG2), dim3(512), LDS_BYTES, stream>>>(xb, wb, out);
    } else {
        dim3 grid(N_TOT / 128, M_TOT / 128);
        qlinear_kernel<<<grid, dim3(256), 0, stream>>>(x, wq, wsc, wzp, out);
    }
}